// Round 5
// baseline (146.910 us; speedup 1.0000x reference)
//
#include <hip/hip_runtime.h>
#include <math.h>

#define N 512
#define D 512
#define NC 10
#define EPSF 1e-8f
#define PITCH 132          // 128 + 4 pad floats
#define FMAGIC 0x1357ACE5u // != 0xAAAAAAAA poison, != 0

// Single fused kernel. grid 256 blocks x 256 threads (1 block/CU; LDS ~58KB
// => capacity 2 blocks/CU => all 256 co-resident, spin-flags cannot deadlock).
__global__ __launch_bounds__(256) void k_fused(
    const float* __restrict__ pred,
    const float* __restrict__ dist_raw,
    const int* __restrict__ target,
    float* __restrict__ G,
    float* __restrict__ inv_n,
    unsigned* __restrict__ flag_inv,
    unsigned* __restrict__ flag_tile,
    float* __restrict__ out) {
  __shared__ __align__(16) float As[32][PITCH];
  __shared__ __align__(16) float Bs[32][PITCH];
  __shared__ __align__(16) float red[4][32][36];
  __shared__ float s_inv[N];
  __shared__ int s_t[N];
  __shared__ float s_p[N];
  __shared__ float s_cp[NC];
  __shared__ float s_nrm[4];
  __shared__ float s_part[4];
  __shared__ int s_np;

  const int b = blockIdx.x;
  const int t = threadIdx.x;
  const int bi = b >> 4, bj = b & 15;

  // ---------------- Phase 0: norms of rows 2b, 2b+1 ----------------
  {
    int which = t >> 7, q = t & 127;  // 128 threads per row, float4 each
    const float* rp = pred + (size_t)(2 * b + which) * D + q * 4;
    float4 v = *(const float4*)rp;
    float ss = v.x * v.x + v.y * v.y + v.z * v.z + v.w * v.w;
    for (int off = 32; off > 0; off >>= 1) ss += __shfl_down(ss, off);
    if ((t & 63) == 0) s_nrm[t >> 6] = ss;
    __syncthreads();
    if (t < 2)
      inv_n[2 * b + t] = 1.0f / fmaxf(sqrtf(s_nrm[2 * t] + s_nrm[2 * t + 1]), EPSF);
    if (b == 0 && t == 0) out[0] = 0.0f;
    __threadfence();   // release: inv_n (and out=0) visible device-wide
    __syncthreads();
    if (t == 0)
      __hip_atomic_store(&flag_inv[b], FMAGIC, __ATOMIC_RELEASE, __HIP_MEMORY_SCOPE_AGENT);
  }

  // ---------------- Phase 1: Gram tile (bi,bj), K split across 4 waves ----
  {
    const int w = t >> 6;
    const int lane = t & 63;
    const int tx = lane & 7, ty = lane >> 3;
    const float* Arow = pred + (size_t)(bi * 32) * D;
    const float* Brow = pred + (size_t)(bj * 32) * D;

    float acc[4][4];
#pragma unroll
    for (int r = 0; r < 4; r++)
#pragma unroll
      for (int c = 0; c < 4; c++) acc[r][c] = 0.0f;

    float4 pa[4], pb[4];
#pragma unroll
    for (int j = 0; j < 4; j++) {
      int f = t + 256 * j;
      int row = f >> 5, k4 = f & 31;
      pa[j] = *(const float4*)(Arow + (size_t)row * D + k4 * 4);
      pb[j] = *(const float4*)(Brow + (size_t)row * D + k4 * 4);
    }

    for (int ch = 0; ch < 4; ch++) {
      __syncthreads();  // protect LDS reuse across iterations
#pragma unroll
      for (int j = 0; j < 4; j++) {
        int f = t + 256 * j;
        int row = f >> 5, k4 = f & 31;
        *(float4*)(&As[row][k4 * 4]) = pa[j];
        *(float4*)(&Bs[row][k4 * 4]) = pb[j];
      }
      __syncthreads();
      if (ch < 3) {
        int k0 = (ch + 1) * 128;
#pragma unroll
        for (int j = 0; j < 4; j++) {
          int f = t + 256 * j;
          int row = f >> 5, k4 = f & 31;
          pa[j] = *(const float4*)(Arow + (size_t)row * D + k0 + k4 * 4);
          pb[j] = *(const float4*)(Brow + (size_t)row * D + k0 + k4 * 4);
        }
      }
      const int kb = w * 32;  // this wave's k-slice of the 128-k chunk
#pragma unroll
      for (int kk = 0; kk < 32; kk += 4) {
        float4 av[4], bv[4];
#pragma unroll
        for (int r = 0; r < 4; r++) av[r] = *(const float4*)(&As[ty + 8 * r][kb + kk]);
#pragma unroll
        for (int c = 0; c < 4; c++) bv[c] = *(const float4*)(&Bs[tx + 8 * c][kb + kk]);
#pragma unroll
        for (int r = 0; r < 4; r++)
#pragma unroll
          for (int c = 0; c < 4; c++)
            acc[r][c] += av[r].x * bv[c].x + av[r].y * bv[c].y +
                         av[r].z * bv[c].z + av[r].w * bv[c].w;
      }
    }
    __syncthreads();

    // cross-wave reduction
#pragma unroll
    for (int r = 0; r < 4; r++)
#pragma unroll
      for (int c = 0; c < 4; c++)
        red[w][ty + 8 * r][tx + 8 * c] = acc[r][c];
    __syncthreads();

    const int m = t >> 3;
    const int n4 = (t & 7) * 4;
    float4 s0 = *(const float4*)(&red[0][m][n4]);
    float4 s1 = *(const float4*)(&red[1][m][n4]);
    float4 s2 = *(const float4*)(&red[2][m][n4]);
    float4 s3 = *(const float4*)(&red[3][m][n4]);
    float4 s;
    s.x = (s0.x + s1.x) + (s2.x + s3.x);
    s.y = (s0.y + s1.y) + (s2.y + s3.y);
    s.z = (s0.z + s1.z) + (s2.z + s3.z);
    s.w = (s0.w + s1.w) + (s2.w + s3.w);
    *(float4*)(&G[(size_t)(bi * 32 + m) * N + bj * 32 + n4]) = s;

    __threadfence();   // release: G tile visible device-wide
    __syncthreads();
    if (t == 0)
      __hip_atomic_store(&flag_tile[b], FMAGIC, __ATOMIC_RELEASE, __HIP_MEMORY_SCOPE_AGENT);
  }

  // ---------------- Phase 2: wait (all inv flags + this strip's 16 tiles) --
  if (t < 64) {
    for (int f = t; f < 256; f += 64)
      while (__hip_atomic_load(&flag_inv[f], __ATOMIC_RELAXED, __HIP_MEMORY_SCOPE_AGENT) != FMAGIC)
        __builtin_amdgcn_s_sleep(1);
    if (t < 16) {
      const int g = (bi << 4) + t;
      while (__hip_atomic_load(&flag_tile[g], __ATOMIC_RELAXED, __HIP_MEMORY_SCOPE_AGENT) != FMAGIC)
        __builtin_amdgcn_s_sleep(1);
    }
  }
  __syncthreads();
  __threadfence();  // acquire: make G / inv_n reads fresh

  // ---------------- Phase 3: loss for rows 2b, 2b+1 ----------------
  s_inv[t] = inv_n[t];
  s_inv[t + 256] = inv_n[t + 256];
  s_t[t] = target[t];
  s_t[t + 256] = target[t + 256];
  if (t == 0) {
    float a = 0.0f;
    s_cp[0] = 0.0f;
    for (int c = 0; c < NC - 1; c++) {
      a += log1pf(expf(dist_raw[c]));
      s_cp[c + 1] = a;
    }
  }
  __syncthreads();

  float contrib = 0.0f;
  for (int rr = 0; rr < 2; rr++) {
    const int i = 2 * b + rr;
    const int ti = s_t[i];
    const float inv_i = s_inv[i];
    const float cpi = s_cp[ti];
    if (t == 0) s_np = 0;
    __syncthreads();
    const int j0 = t, j1 = t + 256;
    float c0 = G[(size_t)i * N + j0] * inv_i * s_inv[j0];
    float c1 = G[(size_t)i * N + j1] * inv_i * s_inv[j1];
    int t0v = s_t[j0], t1v = s_t[j1];
    bool p0 = (t0v == ti), p1 = (t1v == ti);
    float a0 = p0 ? -1e30f : (c0 + fabsf(cpi - s_cp[t0v]));
    float a1 = p1 ? -1e30f : (c1 + fabsf(cpi - s_cp[t1v]));
    if (p0 && j0 != i) { int k = atomicAdd(&s_np, 1); s_p[k] = c0; }
    if (p1 && j1 != i) { int k = atomicAdd(&s_np, 1); s_p[k] = c1; }
    __syncthreads();
    const int np = s_np;
    const int nn = N - np - 1;
    float acc = 0.0f;
    for (int kk = 0; kk < np; kk++) {
      float ck = s_p[kk];  // LDS broadcast
      acc += fmaxf(a0 - ck, 0.0f) + fmaxf(a1 - ck, 0.0f);
    }
    for (int off = 32; off > 0; off >>= 1) acc += __shfl_down(acc, off);
    if ((t & 63) == 0) s_part[t >> 6] = acc;
    __syncthreads();
    if (t == 0 && np > 0 && nn > 0) {
      float tot = s_part[0] + s_part[1] + s_part[2] + s_part[3];
      contrib += tot / ((float)nn * (float)nn * (float)np) * (1.0f / (float)N);
    }
  }
  if (t == 0) atomicAdd(out, contrib);
}

extern "C" void kernel_launch(void* const* d_in, const int* in_sizes, int n_in,
                              void* d_out, int out_size, void* d_ws, size_t ws_size,
                              hipStream_t stream) {
  const float* pred = (const float*)d_in[0];
  const float* dist_raw = (const float*)d_in[1];
  const int* target = (const int*)d_in[2];
  float* out = (float*)d_out;

  float* G = (float*)d_ws;                    // N*N floats
  float* inv_n = G + (size_t)N * N;           // N floats
  unsigned* flag_inv = (unsigned*)(inv_n + N);   // 256 u32
  unsigned* flag_tile = flag_inv + 256;          // 256 u32

  k_fused<<<256, 256, 0, stream>>>(pred, dist_raw, target, G, inv_n,
                                   flag_inv, flag_tile, out);
}

// Round 6
// 95.055 us; speedup vs baseline: 1.5455x; 1.5455x over previous
//
#include <hip/hip_runtime.h>
#include <math.h>

#define N 512
#define D 512
#define NC 10
#define EPSF 1e-8f

// One block per 2 anchor rows (grid 256). Each block independently:
//  - stages its 2 anchor rows in LDS
//  - streams all 512 rows of pred once, computing x0.xj, x1.xj, xj.xj
//    (thread t owns rows t and t+256; LDS anchor reads are same-address
//    broadcasts = conflict-free)
//  - loss phase entirely LDS-local; atomicAdd contribution to out.
// No workspace, no inter-block communication (R5 showed device-scope
// fences/spins cost ~97us on gfx950 - kernel boundary or independence only).
__global__ __launch_bounds__(256) void k_fused(
    const float* __restrict__ pred,
    const float* __restrict__ dist_raw,
    const int* __restrict__ target,
    float* __restrict__ out) {   // pre-zeroed by hipMemsetAsync
  const int b = blockIdx.x;
  const int t = threadIdx.x;
  const int i0 = 2 * b, i1 = 2 * b + 1;

  __shared__ __align__(16) float s_x0[D];
  __shared__ __align__(16) float s_x1[D];
  __shared__ float s_c0[N];   // x0 . xj * inv_j
  __shared__ float s_c1[N];   // x1 . xj * inv_j
  __shared__ int   s_t[N];
  __shared__ float s_p[N];
  __shared__ float s_cp[NC];
  __shared__ float s_inv0, s_inv1;
  __shared__ float s_part[4];
  __shared__ int s_np;

  // ---- stage anchor rows + targets + class_pos ----
  {
    int which = t >> 7, q = t & 127;
    float4 v = *(const float4*)(pred + (size_t)(i0 + which) * D + q * 4);
    if (which == 0) *(float4*)(&s_x0[q * 4]) = v;
    else            *(float4*)(&s_x1[q * 4]) = v;
  }
  s_t[t] = target[t];
  s_t[t + 256] = target[t + 256];
  if (t == 0) {
    float a = 0.0f;
    s_cp[0] = 0.0f;
    for (int c = 0; c < NC - 1; c++) {
      a += log1pf(expf(dist_raw[c]));
      s_cp[c + 1] = a;
    }
  }
  __syncthreads();

  // ---- streaming pass: rows t and t+256 ----
  for (int jj = 0; jj < 2; jj++) {
    const int j = t + jj * 256;
    const float4* rj = (const float4*)(pred + (size_t)j * D);
    float4 a00 = {0, 0, 0, 0}, a01 = {0, 0, 0, 0}, ann = {0, 0, 0, 0};
    float4 buf[8], nbuf[8];
#pragma unroll
    for (int u = 0; u < 8; u++) buf[u] = rj[u];
    for (int g = 0; g < 16; g++) {            // 16 groups x 8 float4 = 512 f
      if (g < 15) {
#pragma unroll
        for (int u = 0; u < 8; u++) nbuf[u] = rj[(g + 1) * 8 + u];
      }
#pragma unroll
      for (int u = 0; u < 8; u++) {
        const int k4 = (g * 8 + u) * 4;
        float4 v = buf[u];
        float4 x0 = *(const float4*)(&s_x0[k4]);  // broadcast
        float4 x1 = *(const float4*)(&s_x1[k4]);  // broadcast
        a00.x += v.x * x0.x; a00.y += v.y * x0.y;
        a00.z += v.z * x0.z; a00.w += v.w * x0.w;
        a01.x += v.x * x1.x; a01.y += v.y * x1.y;
        a01.z += v.z * x1.z; a01.w += v.w * x1.w;
        ann.x += v.x * v.x;  ann.y += v.y * v.y;
        ann.z += v.z * v.z;  ann.w += v.w * v.w;
      }
#pragma unroll
      for (int u = 0; u < 8; u++) buf[u] = nbuf[u];
    }
    float d00 = (a00.x + a00.y) + (a00.z + a00.w);
    float d01 = (a01.x + a01.y) + (a01.z + a01.w);
    float dnn = (ann.x + ann.y) + (ann.z + ann.w);
    float invj = 1.0f / fmaxf(sqrtf(dnn), EPSF);
    s_c0[j] = d00 * invj;
    s_c1[j] = d01 * invj;
    if (j == i0) s_inv0 = invj;
    if (j == i1) s_inv1 = invj;
  }
  __syncthreads();

  // ---- loss phase for rows i0, i1 ----
  float contrib = 0.0f;
#pragma unroll
  for (int rr = 0; rr < 2; rr++) {
    const int i = (rr == 0) ? i0 : i1;
    const float inv_i = (rr == 0) ? s_inv0 : s_inv1;
    const float* s_c = (rr == 0) ? s_c0 : s_c1;
    const int ti = s_t[i];
    const float cpi = s_cp[ti];
    if (t == 0) s_np = 0;
    __syncthreads();
    const int j0 = t, j1 = t + 256;
    const float c0 = s_c[j0] * inv_i;
    const float c1 = s_c[j1] * inv_i;
    const int t0v = s_t[j0], t1v = s_t[j1];
    const bool p0 = (t0v == ti), p1 = (t1v == ti);
    const float a0 = p0 ? -1e30f : (c0 + fabsf(cpi - s_cp[t0v]));
    const float a1 = p1 ? -1e30f : (c1 + fabsf(cpi - s_cp[t1v]));
    if (p0 && j0 != i) { int k = atomicAdd(&s_np, 1); s_p[k] = c0; }
    if (p1 && j1 != i) { int k = atomicAdd(&s_np, 1); s_p[k] = c1; }
    __syncthreads();
    const int np = s_np;
    const int nn = N - np - 1;
    float acc = 0.0f;
    for (int kk = 0; kk < np; kk++) {
      float ck = s_p[kk];  // LDS broadcast
      acc += fmaxf(a0 - ck, 0.0f) + fmaxf(a1 - ck, 0.0f);
    }
    for (int off = 32; off > 0; off >>= 1) acc += __shfl_down(acc, off);
    if ((t & 63) == 0) s_part[t >> 6] = acc;
    __syncthreads();
    if (t == 0 && np > 0 && nn > 0) {
      float tot = s_part[0] + s_part[1] + s_part[2] + s_part[3];
      contrib += tot / ((float)nn * (float)nn * (float)np) * (1.0f / (float)N);
    }
  }
  if (t == 0) atomicAdd(out, contrib);
}

extern "C" void kernel_launch(void* const* d_in, const int* in_sizes, int n_in,
                              void* d_out, int out_size, void* d_ws, size_t ws_size,
                              hipStream_t stream) {
  const float* pred = (const float*)d_in[0];
  const float* dist_raw = (const float*)d_in[1];
  const int* target = (const int*)d_in[2];
  float* out = (float*)d_out;

  hipMemsetAsync(out, 0, sizeof(float), stream);
  k_fused<<<256, 256, 0, stream>>>(pred, dist_raw, target, out);
}

// Round 7
// 83.576 us; speedup vs baseline: 1.7578x; 1.1374x over previous
//
#include <hip/hip_runtime.h>
#include <math.h>

#define N 512
#define D 512
#define NC 10
#define EPSF 1e-8f
#define RED_PITCH 68   // floats; 16B-aligned rows, bank stride 4 -> cheap

// One block per 2 anchor rows (grid 256, 4 waves). Lane l owns k-slice
// [8l, 8l+8) held in registers (anchors too). Each wave processes 128 rows j:
// per row, 2 coalesced dwordx4 loads (32B lane stride over one contiguous
// 2KB row), 24 FMAs -> per-lane partials for (x0.xj, x1.xj, xj.xj).
// Reduction deferred: 16-row batches -> LDS transpose (wave-local, no
// block barrier) -> s_c0/s_c1/s_inv. Loss phase as R6 (verified correct).
// No workspace, no inter-block communication.
__global__ __launch_bounds__(256, 1) void k_fused(
    const float* __restrict__ pred,
    const float* __restrict__ dist_raw,
    const int* __restrict__ target,
    float* __restrict__ out) {   // pre-zeroed by hipMemsetAsync
  const int b = blockIdx.x;
  const int t = threadIdx.x;
  const int w = t >> 6;          // wave 0..3
  const int l = t & 63;          // lane
  const int i0 = 2 * b, i1 = 2 * b + 1;

  __shared__ __align__(16) float s_x0[D];
  __shared__ __align__(16) float s_x1[D];
  __shared__ __align__(16) float s_red[4][48 * RED_PITCH];  // per-wave
  __shared__ float s_c0[N];    // x0 . xj (raw)
  __shared__ float s_c1[N];    // x1 . xj (raw)
  __shared__ float s_inv[N];   // 1/max(||xj||,eps)
  __shared__ int   s_t[N];
  __shared__ float s_p[N];
  __shared__ float s_cp[NC];
  __shared__ float s_part[4];
  __shared__ int s_np;

  // ---- stage anchors + targets + class_pos ----
  {
    int which = t >> 7, q = t & 127;
    float4 v = *(const float4*)(pred + (size_t)(i0 + which) * D + q * 4);
    if (which == 0) *(float4*)(&s_x0[q * 4]) = v;
    else            *(float4*)(&s_x1[q * 4]) = v;
  }
  s_t[t] = target[t];
  s_t[t + 256] = target[t + 256];
  if (t == 0) {
    float a = 0.0f;
    s_cp[0] = 0.0f;
    for (int c = 0; c < NC - 1; c++) {
      a += log1pf(expf(dist_raw[c]));
      s_cp[c + 1] = a;
    }
  }
  __syncthreads();

  // lane-resident anchor slices
  const float4 x0a = *(const float4*)(&s_x0[8 * l]);
  const float4 x0b = *(const float4*)(&s_x0[8 * l + 4]);
  const float4 x1a = *(const float4*)(&s_x1[8 * l]);
  const float4 x1b = *(const float4*)(&s_x1[8 * l + 4]);

  const int jbase = w * 128;           // this wave's 128 rows
  float* red = s_red[w];

  for (int batch = 0; batch < 8; batch++) {
    const int j0r = jbase + batch * 16;
    const float* base = pred + (size_t)j0r * D + 8 * l;

    float c0[16], c1[16], nn[16];

    // pipeline: process rows in pairs, prefetch next pair
    float4 ca0 = *(const float4*)(base);
    float4 ca1 = *(const float4*)(base + 4);
    float4 cb0 = *(const float4*)(base + D);
    float4 cb1 = *(const float4*)(base + D + 4);

#pragma unroll
    for (int pr = 0; pr < 8; pr++) {
      float4 na0, na1, nb0, nb1;
      if (pr < 7) {
        const float* nb = base + (size_t)(2 * pr + 2) * D;
        na0 = *(const float4*)(nb);
        na1 = *(const float4*)(nb + 4);
        nb0 = *(const float4*)(nb + D);
        nb1 = *(const float4*)(nb + D + 4);
      }
      // row 2*pr
      {
        float d0 = ca0.x * x0a.x + ca0.y * x0a.y + ca0.z * x0a.z + ca0.w * x0a.w
                 + ca1.x * x0b.x + ca1.y * x0b.y + ca1.z * x0b.z + ca1.w * x0b.w;
        float d1 = ca0.x * x1a.x + ca0.y * x1a.y + ca0.z * x1a.z + ca0.w * x1a.w
                 + ca1.x * x1b.x + ca1.y * x1b.y + ca1.z * x1b.z + ca1.w * x1b.w;
        float dn = ca0.x * ca0.x + ca0.y * ca0.y + ca0.z * ca0.z + ca0.w * ca0.w
                 + ca1.x * ca1.x + ca1.y * ca1.y + ca1.z * ca1.z + ca1.w * ca1.w;
        c0[2 * pr] = d0; c1[2 * pr] = d1; nn[2 * pr] = dn;
      }
      // row 2*pr+1
      {
        float d0 = cb0.x * x0a.x + cb0.y * x0a.y + cb0.z * x0a.z + cb0.w * x0a.w
                 + cb1.x * x0b.x + cb1.y * x0b.y + cb1.z * x0b.z + cb1.w * x0b.w;
        float d1 = cb0.x * x1a.x + cb0.y * x1a.y + cb0.z * x1a.z + cb0.w * x1a.w
                 + cb1.x * x1b.x + cb1.y * x1b.y + cb1.z * x1b.z + cb1.w * x1b.w;
        float dn = cb0.x * cb0.x + cb0.y * cb0.y + cb0.z * cb0.z + cb0.w * cb0.w
                 + cb1.x * cb1.x + cb1.y * cb1.y + cb1.z * cb1.z + cb1.w * cb1.w;
        c0[2 * pr + 1] = d0; c1[2 * pr + 1] = d1; nn[2 * pr + 1] = dn;
      }
      ca0 = na0; ca1 = na1; cb0 = nb0; cb1 = nb1;
    }

    // ---- wave-local reduction: 48 tasks (16 rows x 3 vals) over 64 lanes ----
#pragma unroll
    for (int r = 0; r < 16; r++) {
      red[(r * 3 + 0) * RED_PITCH + l] = c0[r];
      red[(r * 3 + 1) * RED_PITCH + l] = c1[r];
      red[(r * 3 + 2) * RED_PITCH + l] = nn[r];
    }
    __builtin_amdgcn_wave_barrier();  // order LDS write->read (same wave)
    if (l < 48) {
      const int r = l / 3, v = l - 3 * r;
      const float* src = red + (size_t)l * RED_PITCH;
      float4 s4 = {0, 0, 0, 0};
#pragma unroll
      for (int k = 0; k < 16; k++) {
        float4 p = *(const float4*)(src + 4 * k);
        s4.x += p.x; s4.y += p.y; s4.z += p.z; s4.w += p.w;
      }
      float sum = (s4.x + s4.y) + (s4.z + s4.w);
      const int j = j0r + r;
      if (v == 0)      s_c0[j] = sum;
      else if (v == 1) s_c1[j] = sum;
      else             s_inv[j] = 1.0f / fmaxf(sqrtf(sum), EPSF);
    }
    __builtin_amdgcn_wave_barrier();  // order reads before next batch's writes
  }
  __syncthreads();

  // ---- loss phase for rows i0, i1 (structure verified in R6) ----
  float contrib = 0.0f;
#pragma unroll
  for (int rr = 0; rr < 2; rr++) {
    const int i = (rr == 0) ? i0 : i1;
    const float inv_i = s_inv[i];
    const float* s_c = (rr == 0) ? s_c0 : s_c1;
    const int ti = s_t[i];
    const float cpi = s_cp[ti];
    if (t == 0) s_np = 0;
    __syncthreads();
    const int j0 = t, j1 = t + 256;
    const float c0v = s_c[j0] * s_inv[j0] * inv_i;
    const float c1v = s_c[j1] * s_inv[j1] * inv_i;
    const int t0v = s_t[j0], t1v = s_t[j1];
    const bool p0 = (t0v == ti), p1 = (t1v == ti);
    const float a0 = p0 ? -1e30f : (c0v + fabsf(cpi - s_cp[t0v]));
    const float a1 = p1 ? -1e30f : (c1v + fabsf(cpi - s_cp[t1v]));
    if (p0 && j0 != i) { int k = atomicAdd(&s_np, 1); s_p[k] = c0v; }
    if (p1 && j1 != i) { int k = atomicAdd(&s_np, 1); s_p[k] = c1v; }
    __syncthreads();
    const int np = s_np;
    const int nnn = N - np - 1;
    float acc = 0.0f;
    for (int kk = 0; kk < np; kk++) {
      float ck = s_p[kk];  // LDS broadcast
      acc += fmaxf(a0 - ck, 0.0f) + fmaxf(a1 - ck, 0.0f);
    }
    for (int off = 32; off > 0; off >>= 1) acc += __shfl_down(acc, off);
    if ((t & 63) == 0) s_part[t >> 6] = acc;
    __syncthreads();
    if (t == 0 && np > 0 && nnn > 0) {
      float tot = s_part[0] + s_part[1] + s_part[2] + s_part[3];
      contrib += tot / ((float)nnn * (float)nnn * (float)np) * (1.0f / (float)N);
    }
  }
  if (t == 0) atomicAdd(out, contrib);
}

extern "C" void kernel_launch(void* const* d_in, const int* in_sizes, int n_in,
                              void* d_out, int out_size, void* d_ws, size_t ws_size,
                              hipStream_t stream) {
  const float* pred = (const float*)d_in[0];
  const float* dist_raw = (const float*)d_in[1];
  const int* target = (const int*)d_in[2];
  float* out = (float*)d_out;

  hipMemsetAsync(out, 0, sizeof(float), stream);
  k_fused<<<256, 256, 0, stream>>>(pred, dist_raw, target, out);
}